// Round 2
// baseline (525.702 us; speedup 1.0000x reference)
//
#include <hip/hip_runtime.h>
#include <math.h>

#define BB 2
#define CC 512
#define HH 30
#define WW 40
#define KK 64
#define NPIX (HH*WW)
#define HP 27
#define WP 37
#define NP (HP*WP)
#define LEPS 1e-12f

#define PADW 168      // xn ring row stride (4*40 + 8 pad)
#define SROW 680      // soft slab floats per k (17 rows * 40)
#define NCG 16        // c-groups (32 c each)

// ---------------------------------------------------------------------------
// Kernel 1: per-(b,h) row: channel L2-norm, xn store, logits (K=64) + softmax.
// ---------------------------------------------------------------------------
__global__ __launch_bounds__(512) void k_norm_soft(
    const float* __restrict__ x, const float* __restrict__ convw,
    float* __restrict__ xn, float* __restrict__ soft)
{
  const int h = blockIdx.x, b = blockIdx.y;
  const int t = threadIdx.x;
  __shared__ float xc[64][41];
  __shared__ float cw[64][65];
  __shared__ float Lb[KK][WW + 1];
  __shared__ float psum[12][WW];
  __shared__ float invn[WW];
  __shared__ float mx[WW], Zs[WW];

  const size_t xbase = (size_t)b * CC * NPIX + (size_t)h * WW;

  if (t < 480) {
    const int w = t % 40, part = t / 40;
    float s = 0.f;
    for (int c = part; c < CC; c += 12) {
      const float v = x[xbase + (size_t)c * NPIX + w];
      s = fmaf(v, v, s);
    }
    psum[part][w] = s;
  }
  __syncthreads();
  if (t < 40) {
    float s = 0.f;
    #pragma unroll
    for (int p = 0; p < 12; ++p) s += psum[p][t];
    invn[t] = 1.f / fmaxf(sqrtf(s), LEPS);
  }
  __syncthreads();

  const int k = t & 63, wp = t >> 6;
  float acc[5] = {0.f, 0.f, 0.f, 0.f, 0.f};
  for (int cb = 0; cb < CC; cb += 64) {
    #pragma unroll
    for (int n = 0; n < 5; ++n) {
      const int idx = t + 512 * n;
      const int c = idx / 40, w = idx % 40;
      const float v = x[xbase + (size_t)(cb + c) * NPIX + w] * invn[w];
      xc[c][w] = v;
      xn[xbase + (size_t)(cb + c) * NPIX + w] = v;
    }
    #pragma unroll
    for (int n = 0; n < 8; ++n) {
      const int idx = t + 512 * n;
      const int kk2 = idx >> 6, c2 = idx & 63;
      cw[kk2][c2] = convw[(size_t)kk2 * CC + cb + c2];
    }
    __syncthreads();
    #pragma unroll 1
    for (int c = 0; c < 64; ++c) {
      const float cv = cw[k][c];
      #pragma unroll
      for (int n = 0; n < 5; ++n)
        acc[n] = fmaf(cv, xc[c][wp + 8 * n], acc[n]);
    }
    __syncthreads();
  }
  #pragma unroll
  for (int n = 0; n < 5; ++n) Lb[k][wp + 8 * n] = acc[n];
  __syncthreads();
  if (t < 40) {
    float m = -1e30f;
    for (int kk2 = 0; kk2 < KK; ++kk2) m = fmaxf(m, Lb[kk2][t]);
    float Z = 0.f;
    for (int kk2 = 0; kk2 < KK; ++kk2) Z += expf(Lb[kk2][t] - m);
    mx[t] = m; Zs[t] = Z;
  }
  __syncthreads();
  const size_t sbase = (size_t)b * KK * NPIX + (size_t)h * WW;
  #pragma unroll
  for (int n = 0; n < 5; ++n) {
    const int idx = t + 512 * n;
    const int kk2 = idx / 40, w = idx % 40;
    soft[sbase + (size_t)kk2 * NPIX + w] = expf(Lb[kk2][w] - mx[w]) / Zs[w];
  }
}

// ---------------------------------------------------------------------------
// Kernel G: per-(b,k) global VLAD row, first L2 norm over c.
// ---------------------------------------------------------------------------
__global__ __launch_bounds__(256) void k_global(
    const float* __restrict__ xn, const float* __restrict__ soft,
    const float* __restrict__ cent, float* __restrict__ ghat)
{
  const int k = blockIdx.x, b = blockIdx.y, t = threadIdx.x;
  __shared__ float sb[NPIX];
  __shared__ float red[256];
  const float* srow = soft + ((size_t)b * KK + k) * NPIX;
  for (int i2 = t; i2 < NPIX; i2 += 256) sb[i2] = srow[i2];
  __syncthreads();
  float p = 0.f;
  for (int i2 = t; i2 < NPIX; i2 += 256) p += sb[i2];
  red[t] = p;
  __syncthreads();
  for (int s = 128; s > 0; s >>= 1) { if (t < s) red[t] += red[t + s]; __syncthreads(); }
  const float Sg = red[0];
  __syncthreads();

  const int c0 = t, c1 = t + 256;
  const float* x0 = xn + ((size_t)b * CC + c0) * NPIX;
  const float* x1 = xn + ((size_t)b * CC + c1) * NPIX;
  float a0 = 0.f, a1 = 0.f;
  for (int p4 = 0; p4 < NPIX; p4 += 4) {
    const float4 s4 = *(const float4*)&sb[p4];
    const float4 v0 = *(const float4*)(x0 + p4);
    const float4 v1 = *(const float4*)(x1 + p4);
    a0 = fmaf(s4.x, v0.x, a0); a0 = fmaf(s4.y, v0.y, a0);
    a0 = fmaf(s4.z, v0.z, a0); a0 = fmaf(s4.w, v0.w, a0);
    a1 = fmaf(s4.x, v1.x, a1); a1 = fmaf(s4.y, v1.y, a1);
    a1 = fmaf(s4.z, v1.z, a1); a1 = fmaf(s4.w, v1.w, a1);
  }
  const float g0 = a0 - cent[(size_t)k * CC + c0] * Sg;
  const float g1 = a1 - cent[(size_t)k * CC + c1] * Sg;
  red[t] = g0 * g0 + g1 * g1;
  __syncthreads();
  for (int s = 128; s > 0; s >>= 1) { if (t < s) red[t] += red[t + s]; __syncthreads(); }
  const float inv = 1.f / fmaxf(sqrtf(red[0]), LEPS);
  float* gr = ghat + ((size_t)b * KK + k) * CC;
  gr[c0] = g0 * inv; gr[c1] = g1 * inv;
}

__global__ __launch_bounds__(256) void k_global2(
    const float* __restrict__ ghat, float* __restrict__ outg)
{
  const int b = blockIdx.x, t = threadIdx.x;
  __shared__ float red[256];
  const float* gb = ghat + (size_t)b * KK * CC;
  float p = 0.f;
  for (int i2 = t; i2 < KK * CC; i2 += 256) { const float v = gb[i2]; p = fmaf(v, v, p); }
  red[t] = p;
  __syncthreads();
  for (int s = 128; s > 0; s >>= 1) { if (t < s) red[t] += red[t + s]; __syncthreads(); }
  const float inv = 1.f / fmaxf(sqrtf(red[0]), LEPS);
  for (int i2 = t; i2 < KK * CC; i2 += 256)
    outg[(size_t)b * KK * CC + i2] = gb[i2] * inv;
}

// ---------------------------------------------------------------------------
// Kernel L v3: block = (cg of 32 c, kg of 4 k, b x i-half). Rolling 4-row xn
// ring in LDS laid out [c][ring*40+w] (pad 168) -> lane-j-consecutive reads,
// conflict-free. soft slab resident for the whole i-range. 2 barriers / i.
// PHASE 0: per-c-group partial sum_c raw^2 -> ssq_part (scratch in out buf).
// PHASE 1: raw * fs -> out.
// ---------------------------------------------------------------------------
template<int PHASE>
__global__ __launch_bounds__(320, 4) void k_local2(
    const float* __restrict__ xn, const float* __restrict__ soft,
    const float* __restrict__ cent, float* __restrict__ ssq_part,
    const float* __restrict__ fs, float* __restrict__ out)
{
  const int cg = blockIdx.x;             // 0..15
  const int k0 = blockIdx.y * 4;         // k group
  const int bz = blockIdx.z;             // b*2 + iz
  const int b = bz >> 1, iz = bz & 1;
  const int i0 = iz * 14;
  const int n_i = iz ? 13 : 14;
  const int c0 = cg * 32;
  const int t = threadIdx.x;
  const int c8 = t / 40, j = t % 40;     // 8 c-subgroups x 40 cols

  __shared__ float xn_l[32][PADW];       // [c][ring*40 + w]
  __shared__ float soft_l[4][SROW];      // [k][(row-i0)*40 + w]
  __shared__ float S_l[4][40];
  __shared__ float fs_l[4][40];
  __shared__ float cent_l[4][32];
  __shared__ float red[8][4][40];        // phase0: [c8][k][j]

  // stage soft slab (rows i0 .. min(i0+16, 29))
  {
    const int len = (NPIX - i0 * 40) < SROW ? (NPIX - i0 * 40) : SROW;
    const int nf4 = len >> 2;
    for (int u = t; u < 4 * nf4; u += 320) {
      const int kk = u / nf4, q = u - kk * nf4;
      *(float4*)&soft_l[kk][q * 4] =
        *(const float4*)&soft[((size_t)(b * KK + k0 + kk)) * NPIX + i0 * 40 + q * 4];
    }
  }
  if (t < 128) cent_l[t >> 5][t & 31] = cent[(size_t)(k0 + (t >> 5)) * CC + c0 + (t & 31)];
  // prologue: stage xn rows i0..i0+2 into ring
  {
    const int c = t / 10, q = t % 10;
    for (int rr = 0; rr < 3; ++rr) {
      const int row = i0 + rr;
      *(float4*)&xn_l[c][(row & 3) * 40 + q * 4] =
        *(const float4*)&xn[((size_t)(b * CC + c0 + c)) * NPIX + (size_t)row * 40 + q * 4];
    }
  }
  __syncthreads();

  for (int ii = 0; ii < n_i; ++ii) {
    const int i = i0 + ii;
    // ---- A: stage row i+3; S_l(i); fs_l(i) ----
    {
      const int row = i + 3;
      const int c = t / 10, q = t % 10;
      *(float4*)&xn_l[c][(row & 3) * 40 + q * 4] =
        *(const float4*)&xn[((size_t)(b * CC + c0 + c)) * NPIX + (size_t)row * 40 + q * 4];
    }
    if (t < 160) {
      const int kk = t / 40, jj = t % 40;
      float s = 0.f;
      if (jj < WP) {
        #pragma unroll
        for (int r = 0; r < 4; ++r)
          #pragma unroll
          for (int dx = 0; dx < 4; ++dx)
            s += soft_l[kk][(ii + r) * 40 + jj + dx];
      }
      S_l[kk][jj] = s;
      if (PHASE == 1)
        fs_l[kk][jj] = (jj < WP)
          ? fs[((size_t)(b * KK + k0 + kk)) * NP + (size_t)i * WP + jj] : 0.f;
    }
    __syncthreads();

    // ---- B: compute ----
    float sloc[4] = {0.f, 0.f, 0.f, 0.f};
    if (j < WP) {
      float acc[4][4];
      #pragma unroll
      for (int cc = 0; cc < 4; ++cc)
        #pragma unroll
        for (int kk = 0; kk < 4; ++kk) acc[cc][kk] = 0.f;
      #pragma unroll
      for (int r = 0; r < 4; ++r) {
        const int xo = ((i + r) & 3) * 40 + j;
        const int so = (ii + r) * 40 + j;
        float xv[4][4], sv[4][4];
        #pragma unroll
        for (int cc = 0; cc < 4; ++cc)
          #pragma unroll
          for (int dx = 0; dx < 4; ++dx)
            xv[cc][dx] = xn_l[c8 * 4 + cc][xo + dx];
        #pragma unroll
        for (int kk = 0; kk < 4; ++kk)
          #pragma unroll
          for (int dx = 0; dx < 4; ++dx)
            sv[kk][dx] = soft_l[kk][so + dx];
        #pragma unroll
        for (int cc = 0; cc < 4; ++cc)
          #pragma unroll
          for (int kk = 0; kk < 4; ++kk)
            #pragma unroll
            for (int dx = 0; dx < 4; ++dx)
              acc[cc][kk] = fmaf(xv[cc][dx], sv[kk][dx], acc[cc][kk]);
      }
      #pragma unroll
      for (int kk = 0; kk < 4; ++kk) {
        const float Sv = S_l[kk][j];
        const float fv = (PHASE == 1) ? fs_l[kk][j] : 0.f;
        #pragma unroll
        for (int cc = 0; cc < 4; ++cc) {
          const int c = c0 + c8 * 4 + cc;
          const float raw = fmaf(-cent_l[kk][c8 * 4 + cc], Sv, acc[cc][kk]);
          if (PHASE == 0)
            sloc[kk] = fmaf(raw, raw, sloc[kk]);
          else
            out[((size_t)((b * KK + k0 + kk) * CC + c)) * NP + (size_t)i * WP + j] = raw * fv;
        }
      }
    }
    if (PHASE == 0) {
      #pragma unroll
      for (int kk = 0; kk < 4; ++kk) red[c8][kk][j] = sloc[kk];
    }
    __syncthreads();   // protects ring slot reuse + red

    // ---- C: phase0 partial reduce over the block's 32 c ----
    if (PHASE == 0 && t < 160) {
      const int kk = t / 40, jj = t % 40;
      if (jj < WP) {
        float s = 0.f;
        #pragma unroll
        for (int g = 0; g < 8; ++g) s += red[g][kk][jj];
        ssq_part[(((size_t)(b * KK + k0 + kk)) * NCG + cg) * NP + (size_t)i * WP + jj] = s;
      }
    }
  }
}

// ---------------------------------------------------------------------------
// Kernel NF: sum per-c-group partials, build exact per-(b,k,p) scale.
// ---------------------------------------------------------------------------
__global__ __launch_bounds__(256) void k_nf(
    const float* __restrict__ sp, float* __restrict__ fs)
{
  const int b = blockIdx.y;
  const int p = blockIdx.x * 256 + threadIdx.x;
  if (p >= NP) return;
  float n2s = 0.f;
  for (int k = 0; k < KK; ++k) {
    float sr = 0.f;
    for (int g = 0; g < NCG; ++g)
      sr += sp[(((size_t)(b * KK + k)) * NCG + g) * NP + p];
    const float iv = 1.f / fmaxf(sqrtf(sr) * 0.0625f, LEPS);
    n2s += sr * (1.f / 256.f) * iv * iv;
  }
  const float inv2 = 1.f / fmaxf(sqrtf(n2s), LEPS);
  for (int k = 0; k < KK; ++k) {
    float sr = 0.f;
    for (int g = 0; g < NCG; ++g)
      sr += sp[(((size_t)(b * KK + k)) * NCG + g) * NP + p];
    const float iv = 1.f / fmaxf(sqrtf(sr) * 0.0625f, LEPS);
    fs[((size_t)(b * KK + k)) * NP + p] = 0.0625f * iv * inv2;
  }
}

// ---------------------------------------------------------------------------
extern "C" void kernel_launch(void* const* d_in, const int* in_sizes, int n_in,
                              void* d_out, int out_size, void* d_ws, size_t ws_size,
                              hipStream_t stream)
{
  const float* x     = (const float*)d_in[0];
  const float* convw = (const float*)d_in[1];
  const float* cent  = (const float*)d_in[2];
  float* out = (float*)d_out;
  float* ws  = (float*)d_ws;

  float* xn   = ws;                                  // B*C*NPIX
  float* soft = xn   + (size_t)BB * CC * NPIX;       // B*K*NPIX
  float* fs   = soft + (size_t)BB * KK * NPIX;       // B*K*NP
  float* ghat = fs   + (size_t)BB * KK * NP;         // B*K*C

  // scratch for phase-0 partials: start of the vlad_local region of out,
  // fully overwritten by k_local2<1> afterwards (B*K*NCG*NP floats << out).
  float* ssq_part = out;

  k_norm_soft<<<dim3(HH, BB), 512, 0, stream>>>(x, convw, xn, soft);
  k_global<<<dim3(KK, BB), 256, 0, stream>>>(xn, soft, cent, ghat);
  k_global2<<<dim3(BB), 256, 0, stream>>>(ghat, out + (size_t)BB * KK * CC * NP);
  k_local2<0><<<dim3(NCG, KK / 4, BB * 2), 320, 0, stream>>>(xn, soft, cent, ssq_part, fs, out);
  k_nf<<<dim3((NP + 255) / 256, BB), 256, 0, stream>>>(ssq_part, fs);
  k_local2<1><<<dim3(NCG, KK / 4, BB * 2), 320, 0, stream>>>(xn, soft, cent, ssq_part, fs, out);
}

// Round 4
// 382.067 us; speedup vs baseline: 1.3759x; 1.3759x over previous
//
#include <hip/hip_runtime.h>
#include <math.h>

#define BB 2
#define CC 512
#define HH 30
#define WW 40
#define KK 64
#define NPIX (HH*WW)
#define HP 27
#define WP 37
#define NP (HP*WP)
#define LEPS 1e-12f

#define PADW 168      // xn ring row stride in floats (4*40 + 8 pad)
#define SROW 680      // soft slab floats per k (17 rows * 40)
#define NCG 8         // c-groups (64 c each)

// ---------------------------------------------------------------------------
// Kernel 1: per-(b,h) row: channel L2-norm, xn store, logits (K=64) + softmax.
// ---------------------------------------------------------------------------
__global__ __launch_bounds__(512) void k_norm_soft(
    const float* __restrict__ x, const float* __restrict__ convw,
    float* __restrict__ xn, float* __restrict__ soft)
{
  const int h = blockIdx.x, b = blockIdx.y;
  const int t = threadIdx.x;
  __shared__ float xc[64][41];
  __shared__ float cw[64][65];
  __shared__ float Lb[KK][WW + 1];
  __shared__ float psum[12][WW];
  __shared__ float invn[WW];
  __shared__ float mx[WW], Zs[WW];

  const size_t xbase = (size_t)b * CC * NPIX + (size_t)h * WW;

  if (t < 480) {
    const int w = t % 40, part = t / 40;
    float s = 0.f;
    for (int c = part; c < CC; c += 12) {
      const float v = x[xbase + (size_t)c * NPIX + w];
      s = fmaf(v, v, s);
    }
    psum[part][w] = s;
  }
  __syncthreads();
  if (t < 40) {
    float s = 0.f;
    #pragma unroll
    for (int p = 0; p < 12; ++p) s += psum[p][t];
    invn[t] = 1.f / fmaxf(sqrtf(s), LEPS);
  }
  __syncthreads();

  const int k = t & 63, wp = t >> 6;
  float acc[5] = {0.f, 0.f, 0.f, 0.f, 0.f};
  for (int cb = 0; cb < CC; cb += 64) {
    #pragma unroll
    for (int n = 0; n < 5; ++n) {
      const int idx = t + 512 * n;
      const int c = idx / 40, w = idx % 40;
      const float v = x[xbase + (size_t)(cb + c) * NPIX + w] * invn[w];
      xc[c][w] = v;
      xn[xbase + (size_t)(cb + c) * NPIX + w] = v;
    }
    #pragma unroll
    for (int n = 0; n < 8; ++n) {
      const int idx = t + 512 * n;
      const int kk2 = idx >> 6, c2 = idx & 63;
      cw[kk2][c2] = convw[(size_t)kk2 * CC + cb + c2];
    }
    __syncthreads();
    #pragma unroll 1
    for (int c = 0; c < 64; ++c) {
      const float cv = cw[k][c];
      #pragma unroll
      for (int n = 0; n < 5; ++n)
        acc[n] = fmaf(cv, xc[c][wp + 8 * n], acc[n]);
    }
    __syncthreads();
  }
  #pragma unroll
  for (int n = 0; n < 5; ++n) Lb[k][wp + 8 * n] = acc[n];
  __syncthreads();
  if (t < 40) {
    float m = -1e30f;
    for (int kk2 = 0; kk2 < KK; ++kk2) m = fmaxf(m, Lb[kk2][t]);
    float Z = 0.f;
    for (int kk2 = 0; kk2 < KK; ++kk2) Z += expf(Lb[kk2][t] - m);
    mx[t] = m; Zs[t] = Z;
  }
  __syncthreads();
  const size_t sbase = (size_t)b * KK * NPIX + (size_t)h * WW;
  #pragma unroll
  for (int n = 0; n < 5; ++n) {
    const int idx = t + 512 * n;
    const int kk2 = idx / 40, w = idx % 40;
    soft[sbase + (size_t)kk2 * NPIX + w] = expf(Lb[kk2][w] - mx[w]) / Zs[w];
  }
}

// ---------------------------------------------------------------------------
// Kernel G: per-(b,k) global VLAD row, first L2 norm over c.
// ---------------------------------------------------------------------------
__global__ __launch_bounds__(256) void k_global(
    const float* __restrict__ xn, const float* __restrict__ soft,
    const float* __restrict__ cent, float* __restrict__ ghat)
{
  const int k = blockIdx.x, b = blockIdx.y, t = threadIdx.x;
  __shared__ float sb[NPIX];
  __shared__ float red[256];
  const float* srow = soft + ((size_t)b * KK + k) * NPIX;
  for (int i2 = t; i2 < NPIX; i2 += 256) sb[i2] = srow[i2];
  __syncthreads();
  float p = 0.f;
  for (int i2 = t; i2 < NPIX; i2 += 256) p += sb[i2];
  red[t] = p;
  __syncthreads();
  for (int s = 128; s > 0; s >>= 1) { if (t < s) red[t] += red[t + s]; __syncthreads(); }
  const float Sg = red[0];
  __syncthreads();

  const int c0 = t, c1 = t + 256;
  const float* x0 = xn + ((size_t)b * CC + c0) * NPIX;
  const float* x1 = xn + ((size_t)b * CC + c1) * NPIX;
  float a0 = 0.f, a1 = 0.f;
  for (int p4 = 0; p4 < NPIX; p4 += 4) {
    const float4 s4 = *(const float4*)&sb[p4];
    const float4 v0 = *(const float4*)(x0 + p4);
    const float4 v1 = *(const float4*)(x1 + p4);
    a0 = fmaf(s4.x, v0.x, a0); a0 = fmaf(s4.y, v0.y, a0);
    a0 = fmaf(s4.z, v0.z, a0); a0 = fmaf(s4.w, v0.w, a0);
    a1 = fmaf(s4.x, v1.x, a1); a1 = fmaf(s4.y, v1.y, a1);
    a1 = fmaf(s4.z, v1.z, a1); a1 = fmaf(s4.w, v1.w, a1);
  }
  const float g0 = a0 - cent[(size_t)k * CC + c0] * Sg;
  const float g1 = a1 - cent[(size_t)k * CC + c1] * Sg;
  red[t] = g0 * g0 + g1 * g1;
  __syncthreads();
  for (int s = 128; s > 0; s >>= 1) { if (t < s) red[t] += red[t + s]; __syncthreads(); }
  const float inv = 1.f / fmaxf(sqrtf(red[0]), LEPS);
  float* gr = ghat + ((size_t)b * KK + k) * CC;
  gr[c0] = g0 * inv; gr[c1] = g1 * inv;
}

__global__ __launch_bounds__(256) void k_global2(
    const float* __restrict__ ghat, float* __restrict__ outg)
{
  const int b = blockIdx.x, t = threadIdx.x;
  __shared__ float red[256];
  const float* gb = ghat + (size_t)b * KK * CC;
  float p = 0.f;
  for (int i2 = t; i2 < KK * CC; i2 += 256) { const float v = gb[i2]; p = fmaf(v, v, p); }
  red[t] = p;
  __syncthreads();
  for (int s = 128; s > 0; s >>= 1) { if (t < s) red[t] += red[t + s]; __syncthreads(); }
  const float inv = 1.f / fmaxf(sqrtf(red[0]), LEPS);
  for (int i2 = t; i2 < KK * CC; i2 += 256)
    outg[(size_t)b * KK * CC + i2] = gb[i2] * inv;
}

// ---------------------------------------------------------------------------
// Kernel L v5: block = (cg of 64 c, kg of 4 k, b x i-half). 8c x 4k register
// tile. 4-slot rolling xn ring; prologue stages rows i0..i0+3; per-iter
// prefetch row i+4 into REGISTERS (issued before compute, latency hidden),
// ds-written after barrier 1 (slot (i+4)&3 == i&3, free only after compute).
// compute -> [red write] -> barrier1 -> ring write [+ red reduce] -> barrier2.
// PHASE 0: per-c-group sum_c raw^2 -> sp. PHASE 1: raw * fs -> out.
// ---------------------------------------------------------------------------
template<int PHASE>
__global__ __launch_bounds__(320, 2) void k_local2(
    const float* __restrict__ xn, const float* __restrict__ soft,
    const float* __restrict__ cent, float* __restrict__ sp,
    const float* __restrict__ fs, float* __restrict__ out)
{
  const int cg = blockIdx.x;             // 0..7
  const int k0 = blockIdx.y * 4;         // k group
  const int bz = blockIdx.z;             // b*2 + iz
  const int b = bz >> 1, iz = bz & 1;
  const int i0 = iz * 14;
  const int n_i = iz ? 13 : 14;
  const int c0 = cg * 64;
  const int t = threadIdx.x;
  const int c8 = t / 40, j = t % 40;     // 8 c-subgroups x 40 cols

  __shared__ float xn_l[64][PADW];                       // 43008 B
  __shared__ float soft_l[4][SROW];                      // 10880 B
  __shared__ float cent_l[4][64];                        //  1024 B
  __shared__ float red[PHASE == 0 ? 8*4*40 : 4];         //  5120 B (phase0)

  // stage soft slab
  {
    const int len = (NPIX - i0 * 40) < SROW ? (NPIX - i0 * 40) : SROW;
    const int nf4 = len >> 2;
    for (int u = t; u < 4 * nf4; u += 320) {
      const int kk = u / nf4, q = u - kk * nf4;
      *(float4*)&soft_l[kk][q * 4] =
        *(const float4*)&soft[((size_t)(b * KK + k0 + kk)) * NPIX + i0 * 40 + q * 4];
    }
  }
  if (t < 256) cent_l[t >> 6][t & 63] = cent[(size_t)(k0 + (t >> 6)) * CC + c0 + (t & 63)];

  const int sc = t / 10, sq = t % 10;
  // prologue: stage xn rows i0..i0+3 into ring
  #pragma unroll
  for (int rr = 0; rr < 4; ++rr) {
    const int row = i0 + rr;
    const int slot = (row & 3) * 40 + sq * 4;
    *(float4*)&xn_l[sc][slot] =
      *(const float4*)&xn[((size_t)(b * CC + c0 + sc)) * NPIX + (size_t)row * 40 + sq * 4];
    *(float4*)&xn_l[sc + 32][slot] =
      *(const float4*)&xn[((size_t)(b * CC + c0 + sc + 32)) * NPIX + (size_t)row * 40 + sq * 4];
  }
  __syncthreads();

  for (int ii = 0; ii < n_i; ++ii) {
    const int i = i0 + ii;

    // ---- prefetch row i+4 into registers (written to ring after barrier1)
    const int nrow = (i + 4 < HH) ? (i + 4) : (HH - 1);
    const float4 st0 = *(const float4*)&xn[((size_t)(b * CC + c0 + sc)) * NPIX
                                           + (size_t)nrow * 40 + sq * 4];
    const float4 st1 = *(const float4*)&xn[((size_t)(b * CC + c0 + sc + 32)) * NPIX
                                           + (size_t)nrow * 40 + sq * 4];
    float fsv[4];
    if (PHASE == 1) {
      #pragma unroll
      for (int kk = 0; kk < 4; ++kk)
        fsv[kk] = (j < WP)
          ? fs[((size_t)(b * KK + k0 + kk)) * NP + (size_t)i * WP + j] : 0.f;
    }

    // ---- compute (reads ring rows i..i+3, all staged) ----
    float sloc[4] = {0.f, 0.f, 0.f, 0.f};
    if (j < WP) {
      float acc[8][4];
      float Ssum[4] = {0.f, 0.f, 0.f, 0.f};
      #pragma unroll
      for (int cc = 0; cc < 8; ++cc)
        #pragma unroll
        for (int kk = 0; kk < 4; ++kk) acc[cc][kk] = 0.f;
      #pragma unroll
      for (int r = 0; r < 4; ++r) {
        const int xo = ((i + r) & 3) * 40 + j;
        const int so = (ii + r) * 40 + j;
        float sv[4][4];
        #pragma unroll
        for (int kk = 0; kk < 4; ++kk) {
          #pragma unroll
          for (int dx = 0; dx < 4; ++dx) sv[kk][dx] = soft_l[kk][so + dx];
          Ssum[kk] += (sv[kk][0] + sv[kk][1]) + (sv[kk][2] + sv[kk][3]);
        }
        #pragma unroll
        for (int cc = 0; cc < 8; ++cc) {
          const float x0 = xn_l[c8 * 8 + cc][xo + 0];
          const float x1 = xn_l[c8 * 8 + cc][xo + 1];
          const float x2 = xn_l[c8 * 8 + cc][xo + 2];
          const float x3 = xn_l[c8 * 8 + cc][xo + 3];
          #pragma unroll
          for (int kk = 0; kk < 4; ++kk) {
            float a = acc[cc][kk];
            a = fmaf(x0, sv[kk][0], a);
            a = fmaf(x1, sv[kk][1], a);
            a = fmaf(x2, sv[kk][2], a);
            a = fmaf(x3, sv[kk][3], a);
            acc[cc][kk] = a;
          }
        }
      }
      #pragma unroll
      for (int kk = 0; kk < 4; ++kk) {
        const float Sv = Ssum[kk];
        #pragma unroll
        for (int cc = 0; cc < 8; ++cc) {
          const float raw = fmaf(-cent_l[kk][c8 * 8 + cc], Sv, acc[cc][kk]);
          if (PHASE == 0)
            sloc[kk] = fmaf(raw, raw, sloc[kk]);
          else
            out[((size_t)((b * KK + k0 + kk) * CC + c0 + c8 * 8 + cc)) * NP
                + (size_t)i * WP + j] = raw * fsv[kk];
        }
      }
    }
    if (PHASE == 0) {
      #pragma unroll
      for (int kk = 0; kk < 4; ++kk) red[(c8 * 4 + kk) * 40 + j] = sloc[kk];
    }
    __syncthreads();   // barrier 1: ring slot i&3 free; red complete

    // ---- write prefetched row into slot (i+4)&3 (== i&3) ----
    {
      const int slot = ((i + 4) & 3) * 40 + sq * 4;
      *(float4*)&xn_l[sc][slot] = st0;
      *(float4*)&xn_l[sc + 32][slot] = st1;
    }
    if (PHASE == 0 && t < 160) {
      const int kk = t / 40, jj = t % 40;
      if (jj < WP) {
        float s = 0.f;
        #pragma unroll
        for (int g = 0; g < 8; ++g) s += red[(g * 4 + kk) * 40 + jj];
        sp[(((size_t)(b * KK + k0 + kk)) * NCG + cg) * NP + (size_t)i * WP + jj] = s;
      }
    }
    __syncthreads();   // barrier 2: ring write + red reuse visible/safe
  }
}

// ---------------------------------------------------------------------------
// Kernel NF_a: sum the NCG per-c-group partials -> ssq. Wide grid, coalesced.
// ---------------------------------------------------------------------------
__global__ __launch_bounds__(256) void k_nf_a(
    const float* __restrict__ sp, float* __restrict__ ssq)
{
  const int u = blockIdx.x * 256 + threadIdx.x;
  if (u >= BB * KK * NP) return;
  const int bk = u / NP, p = u - bk * NP;
  float s = 0.f;
  #pragma unroll
  for (int g = 0; g < NCG; ++g)
    s += sp[((size_t)bk * NCG + g) * NP + p];
  ssq[u] = s;
}

// ---------------------------------------------------------------------------
// Kernel NF_b: per (b, 4 pixels): k-parallel scale build with 64-way LDS
// reduce for the cross-k second norm.
// ---------------------------------------------------------------------------
__global__ __launch_bounds__(256) void k_nf_b(
    const float* __restrict__ ssq, float* __restrict__ fs)
{
  const int b = blockIdx.y, t = threadIdx.x;
  const int k = t >> 2, dp = t & 3;
  const int p = blockIdx.x * 4 + dp;
  __shared__ float red[64][4];
  __shared__ float inv2s[4];
  const bool ok = p < NP;
  const float sr = ok ? ssq[((size_t)(b * KK + k)) * NP + p] : 0.f;
  const float iv = 1.f / fmaxf(sqrtf(sr) * 0.0625f, LEPS);
  red[k][dp] = sr * (1.f / 256.f) * iv * iv;
  __syncthreads();
  if (t < 4) {
    float s = 0.f;
    #pragma unroll
    for (int kk = 0; kk < 64; ++kk) s += red[kk][t];
    inv2s[t] = 1.f / fmaxf(sqrtf(s), LEPS);
  }
  __syncthreads();
  if (ok)
    fs[((size_t)(b * KK + k)) * NP + p] = 0.0625f * iv * inv2s[dp];
}

// ---------------------------------------------------------------------------
extern "C" void kernel_launch(void* const* d_in, const int* in_sizes, int n_in,
                              void* d_out, int out_size, void* d_ws, size_t ws_size,
                              hipStream_t stream)
{
  const float* x     = (const float*)d_in[0];
  const float* convw = (const float*)d_in[1];
  const float* cent  = (const float*)d_in[2];
  float* out = (float*)d_out;
  float* ws  = (float*)d_ws;

  float* xn   = ws;                                  // B*C*NPIX
  float* soft = xn   + (size_t)BB * CC * NPIX;       // B*K*NPIX
  float* fs   = soft + (size_t)BB * KK * NPIX;       // B*K*NP
  float* ghat = fs   + (size_t)BB * KK * NP;         // B*K*C
  float* ssq  = ghat + (size_t)BB * KK * CC;         // B*K*NP
  float* sp   = ssq  + (size_t)BB * KK * NP;         // B*K*NCG*NP

  k_norm_soft<<<dim3(HH, BB), 512, 0, stream>>>(x, convw, xn, soft);
  k_global<<<dim3(KK, BB), 256, 0, stream>>>(xn, soft, cent, ghat);
  k_global2<<<dim3(BB), 256, 0, stream>>>(ghat, out + (size_t)BB * KK * CC * NP);
  k_local2<0><<<dim3(NCG, KK / 4, BB * 2), 320, 0, stream>>>(xn, soft, cent, sp, fs, out);
  k_nf_a<<<dim3((BB * KK * NP + 255) / 256), 256, 0, stream>>>(sp, ssq);
  k_nf_b<<<dim3((NP + 3) / 4, BB), 256, 0, stream>>>(ssq, fs);
  k_local2<1><<<dim3(NCG, KK / 4, BB * 2), 320, 0, stream>>>(xn, soft, cent, sp, fs, out);
}